// Round 2
// baseline (242.683 us; speedup 1.0000x reference)
//
#include <hip/hip_runtime.h>

#define NUM_CLASSES 32000
#define EMBED 128
#define NTOK (64 * 4096)
#define CLS_PER_BLK 64
#define NCHUNK (NUM_CLASSES / CLS_PER_BLK)  // 500 chunks of 64 classes
#define CAP 2048                            // tokens/chunk capacity (mean 524, sd 23)

typedef float f32x4 __attribute__((ext_vector_type(4)));

// ---------------------------------------------------------------------------
// Kernel A: bucket tokens by 64-class chunk.
// Entry packs (c_local << 18) | token  (token < 2^18, c_local < 64).
// Mean 524 tokens/bucket, CAP=2048 is ~66 sigma out -> overflow impossible
// for this input; guard anyway to avoid OOB.
// ---------------------------------------------------------------------------
__global__ __launch_bounds__(256) void bucket_kernel(
    const int* __restrict__ x, int* __restrict__ cnt, int* __restrict__ ids) {
  const int t = blockIdx.x * 256 + threadIdx.x;
  const int c = x[t];
  const int chunk = c >> 6;
  const int pos = atomicAdd(&cnt[chunk], 1);
  if (pos < CAP) ids[(chunk << 11) + pos] = ((c & 63) << 18) | t;
}

// ---------------------------------------------------------------------------
// Kernel B: fused transpose+bias (in LDS, per chunk) + dedup'd scatter.
// One block per chunk: stage W[:, c0:c0+64] + b once (16.4 MB total W reads,
// read exactly once chip-wide), then write each token's 512B row from LDS.
// LDS e-major, row stride 65 f32: staging writes and column reads both
// conflict-light (<=4-way).
// ---------------------------------------------------------------------------
__global__ __launch_bounds__(256) void fused_gather_kernel(
    const float* __restrict__ W, const float* __restrict__ bias,
    const int* __restrict__ cnt, const int* __restrict__ ids,
    f32x4* __restrict__ out) {
  __shared__ float lds[EMBED * (CLS_PER_BLK + 1)];
  const int chunk = blockIdx.x;
  const int c0 = chunk << 6;
  const int tid = threadIdx.x;

  // Stage phase: float4 loads, 16 lanes x 16B = one 64-class row per e.
  const int tx4 = tid & 15;
  const int ty = tid >> 4;  // 0..15
  for (int e = ty; e < EMBED; e += 16) {
    const f32x4 w = *reinterpret_cast<const f32x4*>(
        W + (size_t)e * NUM_CLASSES + c0 + 4 * tx4);
    const float bv = bias[e];
    float* dst = &lds[e * (CLS_PER_BLK + 1) + 4 * tx4];
    dst[0] = w.x + bv;
    dst[1] = w.y + bv;
    dst[2] = w.z + bv;
    dst[3] = w.w + bv;
  }
  __syncthreads();

  // Scatter phase: 8 tokens per iteration, 32 lanes x 16B = 512B row each.
  const int n = min(cnt[chunk], CAP);
  const int slot = tid >> 5;  // 0..7
  const int j = tid & 31;     // float4 index within the 128-f32 row
  const int base = chunk << 11;
  for (int i = slot; i < n; i += 8) {
    const int pk = ids[base + i];
    const int t = pk & 0x3FFFF;
    const int cl = pk >> 18;
    f32x4 v;
    v.x = lds[(4 * j + 0) * (CLS_PER_BLK + 1) + cl];
    v.y = lds[(4 * j + 1) * (CLS_PER_BLK + 1) + cl];
    v.z = lds[(4 * j + 2) * (CLS_PER_BLK + 1) + cl];
    v.w = lds[(4 * j + 3) * (CLS_PER_BLK + 1) + cl];
    __builtin_nontemporal_store(v, &out[(size_t)t * 32 + j]);
  }
}

// ---------------------------------------------------------------------------
// Fallback 1: previous best (table in ws + gather) if ws too small for ids.
// ---------------------------------------------------------------------------
__global__ __launch_bounds__(256) void build_table_kernel(
    const float* __restrict__ W, const float* __restrict__ bias,
    float* __restrict__ Wb) {
  __shared__ float lds[EMBED * (CLS_PER_BLK + 1)];
  const int c0 = blockIdx.x * CLS_PER_BLK;
  const int tid = threadIdx.x;
  const int tx = tid & 63;
  const int ty = tid >> 6;
  for (int e = ty; e < EMBED; e += 4) {
    lds[e * (CLS_PER_BLK + 1) + tx] = W[(size_t)e * NUM_CLASSES + c0 + tx];
  }
  __syncthreads();
  const int e = tid & 127;
  const int half = tid >> 7;
  const float bv = bias[e];
  for (int ci = half; ci < CLS_PER_BLK; ci += 2) {
    Wb[(size_t)(c0 + ci) * EMBED + e] = lds[e * (CLS_PER_BLK + 1) + ci] + bv;
  }
}

__global__ __launch_bounds__(256) void gather_kernel(
    const int* __restrict__ x, const float* __restrict__ Wb,
    float* __restrict__ out) {
  const int g = blockIdx.x * 256 + threadIdx.x;
  const int token = g >> 5;
  const int j = g & 31;
  const int c = x[token];
  reinterpret_cast<f32x4*>(out)[g] =
      reinterpret_cast<const f32x4*>(Wb)[(size_t)c * 32 + j];
}

// ---------------------------------------------------------------------------
// Fallback 2: no usable workspace at all.
// ---------------------------------------------------------------------------
__global__ __launch_bounds__(256) void direct_kernel(
    const int* __restrict__ x, const float* __restrict__ W,
    const float* __restrict__ bias, float* __restrict__ out) {
  const int g = blockIdx.x * 256 + threadIdx.x;
  const int token = g >> 7;
  const int e = g & 127;
  const int c = x[token];
  out[g] = W[(size_t)e * NUM_CLASSES + c] + bias[e];
}

extern "C" void kernel_launch(void* const* d_in, const int* in_sizes, int n_in,
                              void* d_out, int out_size, void* d_ws,
                              size_t ws_size, hipStream_t stream) {
  const int* x = (const int*)d_in[0];
  const float* W = (const float*)d_in[1];
  const float* bias = (const float*)d_in[2];
  float* out = (float*)d_out;

  const size_t need_bucket = 4096 + (size_t)NCHUNK * CAP * sizeof(int);
  const size_t table_bytes = (size_t)NUM_CLASSES * EMBED * sizeof(float);

  if (ws_size >= need_bucket) {
    int* cnt = (int*)d_ws;
    int* ids = (int*)((char*)d_ws + 4096);
    (void)hipMemsetAsync(cnt, 0, NCHUNK * sizeof(int), stream);
    bucket_kernel<<<NTOK / 256, 256, 0, stream>>>(x, cnt, ids);
    fused_gather_kernel<<<NCHUNK, 256, 0, stream>>>(W, bias, cnt, ids,
                                                    (f32x4*)out);
  } else if (ws_size >= table_bytes) {
    float* Wb = (float*)d_ws;
    build_table_kernel<<<NUM_CLASSES / CLS_PER_BLK, 256, 0, stream>>>(W, bias,
                                                                      Wb);
    gather_kernel<<<(NTOK * 32) / 256, 256, 0, stream>>>(x, Wb, out);
  } else {
    direct_kernel<<<(NTOK * EMBED) / 256, 256, 0, stream>>>(x, W, bias, out);
  }
}

// Round 3
// 185.985 us; speedup vs baseline: 1.3049x; 1.3049x over previous
//
#include <hip/hip_runtime.h>

#define NUM_CLASSES 32000
#define EMBED 128
#define NTOK (64 * 4096)
#define CLS_PER_BLK 64
#define NCHUNK (NUM_CLASSES / CLS_PER_BLK)  // 500 chunks of 64 classes
#define NREP 16                             // counter replicas per chunk
#define SUBCAP 96                           // tokens per (chunk,replica); mean 32.8
#define LDS_STRIDE 132                      // 128 + 4, keeps 16B alignment

typedef float f32x4 __attribute__((ext_vector_type(4)));

// ---------------------------------------------------------------------------
// Kernel A: bucket tokens by 64-class chunk, 16-way replicated counters.
// R2 post-mortem: packed cnt[500] = 31 cache lines x 8400 same-line
// return-atomics ~= 84 us of TCC serialization. Fix: replica = blockIdx&15
// and ONE COUNTER PER 64B LINE -> max ~33 atomics/line, fully TLP-hidden.
// Entry packs (c_local << 18) | token  (token < 2^18 = 262144 exactly).
// ---------------------------------------------------------------------------
__global__ __launch_bounds__(256) void bucket_kernel(
    const int* __restrict__ x, int* __restrict__ cnt, int* __restrict__ ids,
    const float* __restrict__ W, const float* __restrict__ bias,
    float* __restrict__ out) {
  const int t = blockIdx.x * 256 + threadIdx.x;
  const int c = x[t];
  const int idx = (c >> 6) * NREP + (blockIdx.x & (NREP - 1));
  const int pos = atomicAdd(&cnt[idx * 16], 1);  // *16: one counter per line
  if (pos < SUBCAP) {
    ids[idx * SUBCAP + pos] = ((c & 63) << 18) | t;
  } else {
    // ~1e-24 probability overflow path: exact direct write, never drops.
    for (int e = 0; e < EMBED; ++e)
      out[(size_t)t * EMBED + e] = W[(size_t)e * NUM_CLASSES + c] + bias[e];
  }
}

// ---------------------------------------------------------------------------
// Kernel B: fused transpose+bias (LDS, per chunk) + dedup'd scatter.
// One block per chunk: stage W[:, c0:c0+64] + b once (16.4 MB chip-wide),
// then write each token's 512B row from LDS.
// LDS class-major stride 132: scatter read is ONE aligned ds_read_b128 per
// lane, conflict-free; staging pays strided scalar writes once per block.
// ---------------------------------------------------------------------------
__global__ __launch_bounds__(256) void fused_gather_kernel(
    const float* __restrict__ W, const float* __restrict__ bias,
    const int* __restrict__ cnt, const int* __restrict__ ids,
    f32x4* __restrict__ out) {
  __shared__ float lds[CLS_PER_BLK * LDS_STRIDE];  // 33 KB
  const int chunk = blockIdx.x;
  const int c0 = chunk << 6;
  const int tid = threadIdx.x;

  // Stage phase: thread (tx4,ty) reads 4 classes of embed-row e, transposes.
  const int tx4 = tid & 15;
  const int ty = tid >> 4;  // 0..15
  for (int e = ty; e < EMBED; e += 16) {
    const f32x4 w = *reinterpret_cast<const f32x4*>(
        W + (size_t)e * NUM_CLASSES + c0 + 4 * tx4);
    const float bv = bias[e];
    lds[(4 * tx4 + 0) * LDS_STRIDE + e] = w.x + bv;
    lds[(4 * tx4 + 1) * LDS_STRIDE + e] = w.y + bv;
    lds[(4 * tx4 + 2) * LDS_STRIDE + e] = w.z + bv;
    lds[(4 * tx4 + 3) * LDS_STRIDE + e] = w.w + bv;
  }
  __syncthreads();

  // Scatter phase: 8 tokens in flight, 32 lanes x 16B = 512B row per token.
  const int slot = tid >> 5;  // 0..7
  const int j = tid & 31;     // f32x4 index within the 128-f32 row
  for (int r = 0; r < NREP; ++r) {
    const int idx = chunk * NREP + r;
    const int n = min(cnt[idx * 16], SUBCAP);
    const int base = idx * SUBCAP;
    for (int i = slot; i < n; i += 8) {
      const int pk = ids[base + i];
      const int t = pk & 0x3FFFF;
      const int cl = pk >> 18;
      const f32x4 v =
          *reinterpret_cast<const f32x4*>(&lds[cl * LDS_STRIDE + 4 * j]);
      __builtin_nontemporal_store(v, &out[(size_t)t * 32 + j]);
    }
  }
}

// ---------------------------------------------------------------------------
// Fallback 1: table in ws + gather (the 177us baseline path).
// ---------------------------------------------------------------------------
__global__ __launch_bounds__(256) void build_table_kernel(
    const float* __restrict__ W, const float* __restrict__ bias,
    float* __restrict__ Wb) {
  __shared__ float lds[EMBED * (CLS_PER_BLK + 1)];
  const int c0 = blockIdx.x * CLS_PER_BLK;
  const int tid = threadIdx.x;
  const int tx = tid & 63;
  const int ty = tid >> 6;
  for (int e = ty; e < EMBED; e += 4) {
    lds[e * (CLS_PER_BLK + 1) + tx] = W[(size_t)e * NUM_CLASSES + c0 + tx];
  }
  __syncthreads();
  const int e = tid & 127;
  const int half = tid >> 7;
  const float bv = bias[e];
  for (int ci = half; ci < CLS_PER_BLK; ci += 2) {
    Wb[(size_t)(c0 + ci) * EMBED + e] = lds[e * (CLS_PER_BLK + 1) + ci] + bv;
  }
}

__global__ __launch_bounds__(256) void gather_kernel(
    const int* __restrict__ x, const float* __restrict__ Wb,
    float* __restrict__ out) {
  const int g = blockIdx.x * 256 + threadIdx.x;
  const int token = g >> 5;
  const int j = g & 31;
  const int c = x[token];
  reinterpret_cast<f32x4*>(out)[g] =
      reinterpret_cast<const f32x4*>(Wb)[(size_t)c * 32 + j];
}

// ---------------------------------------------------------------------------
// Fallback 2: no usable workspace at all.
// ---------------------------------------------------------------------------
__global__ __launch_bounds__(256) void direct_kernel(
    const int* __restrict__ x, const float* __restrict__ W,
    const float* __restrict__ bias, float* __restrict__ out) {
  const int g = blockIdx.x * 256 + threadIdx.x;
  const int token = g >> 7;
  const int e = g & 127;
  const int c = x[token];
  out[g] = W[(size_t)e * NUM_CLASSES + c] + bias[e];
}

extern "C" void kernel_launch(void* const* d_in, const int* in_sizes, int n_in,
                              void* d_out, int out_size, void* d_ws,
                              size_t ws_size, hipStream_t stream) {
  const int* x = (const int*)d_in[0];
  const float* W = (const float*)d_in[1];
  const float* bias = (const float*)d_in[2];
  float* out = (float*)d_out;

  const size_t cnt_bytes = (size_t)NCHUNK * NREP * 16 * sizeof(int);  // 512 KB
  const size_t ids_bytes = (size_t)NCHUNK * NREP * SUBCAP * sizeof(int);
  const size_t need_bucket = cnt_bytes + ids_bytes;  // ~3.6 MB
  const size_t table_bytes = (size_t)NUM_CLASSES * EMBED * sizeof(float);

  if (ws_size >= need_bucket) {
    int* cnt = (int*)d_ws;
    int* ids = (int*)((char*)d_ws + cnt_bytes);
    (void)hipMemsetAsync(cnt, 0, cnt_bytes, stream);
    bucket_kernel<<<NTOK / 256, 256, 0, stream>>>(x, cnt, ids, W, bias, out);
    fused_gather_kernel<<<NCHUNK, 256, 0, stream>>>(W, bias, cnt, ids,
                                                    (f32x4*)out);
  } else if (ws_size >= table_bytes) {
    float* Wb = (float*)d_ws;
    build_table_kernel<<<NUM_CLASSES / CLS_PER_BLK, 256, 0, stream>>>(W, bias,
                                                                      Wb);
    gather_kernel<<<(NTOK * 32) / 256, 256, 0, stream>>>(x, Wb, out);
  } else {
    direct_kernel<<<(NTOK * EMBED) / 256, 256, 0, stream>>>(x, W, bias, out);
  }
}

// Round 5
// 174.518 us; speedup vs baseline: 1.3906x; 1.0657x over previous
//
#include <hip/hip_runtime.h>

#define NUM_CLASSES 32000
#define EMBED 128
#define NTOK (64 * 4096)
#define CLS_PER_BLK 64
#define NCHUNK (NUM_CLASSES / CLS_PER_BLK)  // 500 chunks of 64 classes
#define NREP 16                             // counter replicas per chunk
#define SUBCAP 96                           // tokens per (chunk,replica); mean 32.8
#define LDS_STRIDE 132                      // 128 + 4 floats; 16B-aligned rows

typedef float f32x4 __attribute__((ext_vector_type(4)));

// ---------------------------------------------------------------------------
// Kernel A: bucket tokens by 64-class chunk, 16-way replicated counters,
// one counter per 64B line (R2 lesson: packed counters = 84us of same-line
// return-atomic serialization; spread = TLP-hidden).
// Entry packs (c_local << 18) | token  (token < 2^18 = 262144 exactly).
// ---------------------------------------------------------------------------
__global__ __launch_bounds__(256) void bucket_kernel(
    const int* __restrict__ x, int* __restrict__ cnt, int* __restrict__ ids,
    const float* __restrict__ W, const float* __restrict__ bias,
    float* __restrict__ out) {
  const int t = blockIdx.x * 256 + threadIdx.x;
  const int c = x[t];
  const int idx = (c >> 6) * NREP + (blockIdx.x & (NREP - 1));
  const int pos = atomicAdd(&cnt[idx * 16], 1);  // *16: one counter per line
  if (pos < SUBCAP) {
    ids[idx * SUBCAP + pos] = ((c & 63) << 18) | t;
  } else {
    // ~1e-24 probability overflow path: exact direct write, never drops.
    for (int e = 0; e < EMBED; ++e)
      out[(size_t)t * EMBED + e] = W[(size_t)e * NUM_CLASSES + c] + bias[e];
  }
}

// ---------------------------------------------------------------------------
// Kernel B: fused transpose+bias (LDS tile, one block per 64-class chunk)
// + dedup'd scatter. R3 lesson: the scatter loop was latency-bound
// (dependent global ids load per iteration, 2 waves/SIMD). Fix:
//   * 512 threads (8 waves, 16 token-slots in flight)
//   * token list staged into LDS up front (dense, prefix-summed) so the
//     inner loop is pure LDS->store with no global latency in the chain.
// ---------------------------------------------------------------------------
__global__ __launch_bounds__(512) void fused_gather_kernel(
    const float* __restrict__ W, const float* __restrict__ bias,
    const int* __restrict__ cnt, const int* __restrict__ ids,
    f32x4* __restrict__ out) {
  __shared__ float lds[CLS_PER_BLK * LDS_STRIDE];  // 33 KB
  __shared__ int s_ids[NREP * SUBCAP];             // 6 KB dense token list
  __shared__ int s_cnt[NREP];
  __shared__ int s_ofs[NREP + 1];

  const int chunk = blockIdx.x;
  const int c0 = chunk << 6;
  const int tid = threadIdx.x;

  // Replica counts (16 parallel loads).
  if (tid < NREP) s_cnt[tid] = min(cnt[(chunk * NREP + tid) * 16], SUBCAP);

  // Stage phase: thread (tx4,ty) reads 4 classes of embed-row e, transposes.
  const int tx4 = tid & 15;
  const int ty = tid >> 4;  // 0..31
  for (int e = ty; e < EMBED; e += 32) {
    const f32x4 w = *reinterpret_cast<const f32x4*>(
        W + (size_t)e * NUM_CLASSES + c0 + 4 * tx4);
    const float bv = bias[e];
    lds[(4 * tx4 + 0) * LDS_STRIDE + e] = w.x + bv;
    lds[(4 * tx4 + 1) * LDS_STRIDE + e] = w.y + bv;
    lds[(4 * tx4 + 2) * LDS_STRIDE + e] = w.z + bv;
    lds[(4 * tx4 + 3) * LDS_STRIDE + e] = w.w + bv;
  }
  __syncthreads();

  // Tiny serial prefix over 16 counts.
  if (tid == 0) {
    int acc = 0;
    for (int r = 0; r < NREP; ++r) {
      s_ofs[r] = acc;
      acc += s_cnt[r];
    }
    s_ofs[NREP] = acc;
  }
  __syncthreads();

  // Compact the 16 sub-lists into one dense LDS list: one 32-lane group
  // per replica (~33 entries each, 1-2 coalesced iterations).
  {
    const int r = tid >> 5;     // 0..15
    const int lane = tid & 31;
    const int nr = s_cnt[r];
    const int o = s_ofs[r];
    const int gbase = (chunk * NREP + r) * SUBCAP;
    for (int i = lane; i < nr; i += 32) s_ids[o + i] = ids[gbase + i];
  }
  __syncthreads();

  // Scatter phase: 16 tokens in flight, 32 lanes x 16B = 512B row per token.
  // Inner loop touches only LDS + the output stream -> unroll/ILP hides all.
  const int nTot = s_ofs[NREP];
  const int slot = tid >> 5;  // 0..15
  const int j = tid & 31;     // f32x4 index within the 128-f32 row
  for (int i = slot; i < nTot; i += 16) {
    const int pk = s_ids[i];
    const int t = pk & 0x3FFFF;
    const int cl = pk >> 18;
    const f32x4 v =
        *reinterpret_cast<const f32x4*>(&lds[cl * LDS_STRIDE + 4 * j]);
    __builtin_nontemporal_store(v, &out[(size_t)t * 32 + j]);
  }
}

// ---------------------------------------------------------------------------
// Fallback 1: table in ws + gather (the 177us baseline path).
// ---------------------------------------------------------------------------
__global__ __launch_bounds__(256) void build_table_kernel(
    const float* __restrict__ W, const float* __restrict__ bias,
    float* __restrict__ Wb) {
  __shared__ float lds[EMBED * (CLS_PER_BLK + 1)];
  const int c0 = blockIdx.x * CLS_PER_BLK;
  const int tid = threadIdx.x;
  const int tx = tid & 63;
  const int ty = tid >> 6;
  for (int e = ty; e < EMBED; e += 4) {
    lds[e * (CLS_PER_BLK + 1) + tx] = W[(size_t)e * NUM_CLASSES + c0 + tx];
  }
  __syncthreads();
  const int e = tid & 127;
  const int half = tid >> 7;
  const float bv = bias[e];
  for (int ci = half; ci < CLS_PER_BLK; ci += 2) {
    Wb[(size_t)(c0 + ci) * EMBED + e] = lds[e * (CLS_PER_BLK + 1) + ci] + bv;
  }
}

__global__ __launch_bounds__(256) void gather_kernel(
    const int* __restrict__ x, const float* __restrict__ Wb,
    float* __restrict__ out) {
  const int g = blockIdx.x * 256 + threadIdx.x;
  const int token = g >> 5;
  const int j = g & 31;
  const int c = x[token];
  reinterpret_cast<f32x4*>(out)[g] =
      reinterpret_cast<const f32x4*>(Wb)[(size_t)c * 32 + j];
}

// ---------------------------------------------------------------------------
// Fallback 2: no usable workspace at all.
// ---------------------------------------------------------------------------
__global__ __launch_bounds__(256) void direct_kernel(
    const int* __restrict__ x, const float* __restrict__ W,
    const float* __restrict__ bias, float* __restrict__ out) {
  const int g = blockIdx.x * 256 + threadIdx.x;
  const int token = g >> 7;
  const int e = g & 127;
  const int c = x[token];
  out[g] = W[(size_t)e * NUM_CLASSES + c] + bias[e];
}

extern "C" void kernel_launch(void* const* d_in, const int* in_sizes, int n_in,
                              void* d_out, int out_size, void* d_ws,
                              size_t ws_size, hipStream_t stream) {
  const int* x = (const int*)d_in[0];
  const float* W = (const float*)d_in[1];
  const float* bias = (const float*)d_in[2];
  float* out = (float*)d_out;

  const size_t cnt_bytes = (size_t)NCHUNK * NREP * 16 * sizeof(int);  // 512 KB
  const size_t ids_bytes = (size_t)NCHUNK * NREP * SUBCAP * sizeof(int);
  const size_t need_bucket = cnt_bytes + ids_bytes;  // ~3.6 MB
  const size_t table_bytes = (size_t)NUM_CLASSES * EMBED * sizeof(float);

  if (ws_size >= need_bucket) {
    int* cnt = (int*)d_ws;
    int* ids = (int*)((char*)d_ws + cnt_bytes);
    (void)hipMemsetAsync(cnt, 0, cnt_bytes, stream);
    bucket_kernel<<<NTOK / 256, 256, 0, stream>>>(x, cnt, ids, W, bias, out);
    fused_gather_kernel<<<NCHUNK, 512, 0, stream>>>(W, bias, cnt, ids,
                                                    (f32x4*)out);
  } else if (ws_size >= table_bytes) {
    float* Wb = (float*)d_ws;
    build_table_kernel<<<NUM_CLASSES / CLS_PER_BLK, 256, 0, stream>>>(W, bias,
                                                                      Wb);
    gather_kernel<<<(NTOK * 32) / 256, 256, 0, stream>>>(x, Wb, out);
  } else {
    direct_kernel<<<(NTOK * EMBED) / 256, 256, 0, stream>>>(x, W, bias, out);
  }
}